// Round 1
// baseline (187.471 us; speedup 1.0000x reference)
//
#include <hip/hip_runtime.h>
#include <hip/hip_bf16.h>
#include <math.h>

// Problem constants
#define B_     128
#define S_     4096
#define PMAX_  256
#define HID_   1024
#define INDIM_ 272
#define KPAD_  288          // 272 padded to 9*32 for the MFMA K-loop
#define M_     (B_ * PMAX_) // 32768 rows
#define N_     1024

typedef __bf16 bf16x8 __attribute__((ext_vector_type(8)));
typedef float  f32x4  __attribute__((ext_vector_type(4)));

// ---------------------------------------------------------------- prep ----

// W1 (272 x 1024) f32  ->  w1t (1024 x 288) bf16, zero-padded K
__global__ void prep_w1(const float* __restrict__ W1, __hip_bfloat16* __restrict__ w1t) {
    int gid = blockIdx.x * 256 + threadIdx.x;
    if (gid >= N_ * KPAD_) return;
    int n = gid / KPAD_;
    int k = gid - n * KPAD_;
    float v = (k < INDIM_) ? W1[(long)k * N_ + n] : 0.0f;
    w1t[gid] = __float2bfloat16(v);
}

// W2 (1024 x 1024) f32 -> w2t (1024 x 1024) bf16 transposed
__global__ void prep_w2(const float* __restrict__ W2, __hip_bfloat16* __restrict__ w2t) {
    int gid = blockIdx.x * 256 + threadIdx.x;   // exactly 1M threads
    int n = gid >> 10;
    int k = gid & 1023;
    w2t[gid] = __float2bfloat16(W2[(long)k * N_ + n]);
}

__global__ void write_npatch(const int* __restrict__ lengths, float* __restrict__ np_out) {
    int b = threadIdx.x;
    if (b < B_) np_out[b] = (float)((lengths[b] + 15) >> 4);
}

// feat (32768 x 288) bf16:
//  k <  16  : vals gathered with clamp-to-last-valid
//  16..271  : pos_table[pos, e] with pos = t if t < L else PAD(4096)
//  272..287 : zero pad
__global__ void build_feat(const float* __restrict__ x,
                           const int* __restrict__ lengths,
                           const float* __restrict__ pos_table,
                           __hip_bfloat16* __restrict__ feat) {
    int m = blockIdx.x;          // 0..32767 : b*256 + p
    int k = threadIdx.x;         // 0..319 (320 threads, 5 waves)
    if (k >= KPAD_) return;
    int b = m >> 8;
    int p = m & 255;
    int L = lengths[b];
    float v = 0.0f;
    if (k < 16) {
        int t = p * 16 + k;
        int idx = (t < L) ? t : (L - 1);
        v = x[((long)b * S_ + idx) * 2];          // x[b, idx, 0]
    } else if (k < INDIM_) {
        int q = k - 16;
        int t = p * 16 + (q >> 4);
        int pos = (t < L) ? t : S_;               // PAD_IDX = 4096
        v = pos_table[pos * 16 + (q & 15)];
    }
    feat[(long)m * KPAD_ + k] = __float2bfloat16(v);
}

// ---------------------------------------------------------------- GEMM ----

__device__ __forceinline__ void gl_lds16(const __hip_bfloat16* g, __hip_bfloat16* l) {
    __builtin_amdgcn_global_load_lds(
        (const __attribute__((address_space(1))) unsigned int*)g,
        (__attribute__((address_space(3))) unsigned int*)l, 16, 0, 0);
}

// C(M x 1024) = A(M x K) @ BT(1024 x K)^T, 128x128 tile, 4 waves, 16x16x32 bf16 MFMA.
// MODE 0: h = bf16(gelu(C + bias))       -> HOut
// MODE 1: out = f32((C + bias) * mask)   -> FOut
template <int MODE>
__global__ __launch_bounds__(256) void gemm_bt(const __hip_bfloat16* __restrict__ A,
                                               const __hip_bfloat16* __restrict__ BT,
                                               const float* __restrict__ bias,
                                               const int* __restrict__ lengths,
                                               __hip_bfloat16* __restrict__ HOut,
                                               float* __restrict__ FOut,
                                               int K) {
    __shared__ __hip_bfloat16 As[128 * 32];
    __shared__ __hip_bfloat16 Bs[128 * 32];

    const int tid  = threadIdx.x;
    const int bm   = blockIdx.x;      // M tile (256)
    const int bn   = blockIdx.y;      // N tile (8)
    const long arow0 = (long)bm * 128;
    const int  brow0 = bn * 128;

    const int wave = tid >> 6;
    const int lane = tid & 63;
    const int wr = wave >> 1, wc = wave & 1;   // 2x2 waves of 64x64
    const int fr = lane & 15;                  // fragment row (A) / col (B)
    const int kg = lane >> 4;                  // k-group 0..3

    f32x4 acc[4][4] = {};

    // staging: 512 chunks of 16B per tile; chunk i -> row i>>2, col8 (i&3)*8
    const int i0 = tid, i1 = 256 + tid;
    const int r0 = i0 >> 2, c0 = (i0 & 3) * 8;
    const int r1 = i1 >> 2, c1 = (i1 & 3) * 8;

    const __hip_bfloat16* Abase = A + arow0 * K;
    const __hip_bfloat16* Bbase = BT + (long)brow0 * K;

    for (int k0 = 0; k0 < K; k0 += 32) {
        gl_lds16(Abase + (long)r0 * K + k0 + c0, As + i0 * 8);
        gl_lds16(Abase + (long)r1 * K + k0 + c1, As + i1 * 8);
        gl_lds16(Bbase + (long)r0 * K + k0 + c0, Bs + i0 * 8);
        gl_lds16(Bbase + (long)r1 * K + k0 + c1, Bs + i1 * 8);
        __syncthreads();   // drains vmcnt: tiles resident

        bf16x8 af[4], bfr[4];
#pragma unroll
        for (int mi = 0; mi < 4; ++mi)
            af[mi] = *(const bf16x8*)(As + (wr * 64 + mi * 16 + fr) * 32 + kg * 8);
#pragma unroll
        for (int ni = 0; ni < 4; ++ni)
            bfr[ni] = *(const bf16x8*)(Bs + (wc * 64 + ni * 16 + fr) * 32 + kg * 8);
#pragma unroll
        for (int mi = 0; mi < 4; ++mi)
#pragma unroll
            for (int ni = 0; ni < 4; ++ni)
                acc[mi][ni] = __builtin_amdgcn_mfma_f32_16x16x32_bf16(
                    af[mi], bfr[ni], acc[mi][ni], 0, 0, 0);
        __syncthreads();   // LDS reads done before next stage overwrites
    }

    // epilogue: lane holds C[row = base + kg*4 + r][col = base + fr]
#pragma unroll
    for (int ni = 0; ni < 4; ++ni) {
        const int col = bn * 128 + wc * 64 + ni * 16 + fr;
        const float bv = bias[col];
#pragma unroll
        for (int mi = 0; mi < 4; ++mi) {
#pragma unroll
            for (int r = 0; r < 4; ++r) {
                const long row = arow0 + wr * 64 + mi * 16 + kg * 4 + r;
                float v = acc[mi][ni][r] + bv;
                if (MODE == 0) {
                    float g = 0.5f * v * (1.0f + erff(v * 0.70710678118f));
                    HOut[row * N_ + col] = __float2bfloat16(g);
                } else {
                    const int bb = (int)(row >> 8);
                    const int pp = (int)(row & 255);
                    const int np = (lengths[bb] + 15) >> 4;
                    FOut[row * N_ + col] = (pp < np) ? v : 0.0f;
                }
            }
        }
    }
}

// -------------------------------------------------------------- launch ----

extern "C" void kernel_launch(void* const* d_in, const int* in_sizes, int n_in,
                              void* d_out, int out_size, void* d_ws, size_t ws_size,
                              hipStream_t stream) {
    const float* x         = (const float*)d_in[0];
    const int*   lengths   = (const int*)d_in[1];
    const float* pos_table = (const float*)d_in[2];
    const float* W1        = (const float*)d_in[3];
    const float* b1        = (const float*)d_in[4];
    const float* W2        = (const float*)d_in[5];
    const float* b2        = (const float*)d_in[6];
    float* out = (float*)d_out;

    char* ws = (char*)d_ws;
    __hip_bfloat16* w1t  = (__hip_bfloat16*)(ws);             // 1024*288*2  = 589824 B
    __hip_bfloat16* w2t  = (__hip_bfloat16*)(ws + 589824);    // 1024*1024*2 = 2097152 B
    __hip_bfloat16* feat = (__hip_bfloat16*)(ws + 2686976);   // 32768*288*2 = 18874368 B
    __hip_bfloat16* h    = (__hip_bfloat16*)(ws + 21561344);  // 32768*1024*2 = 67108864 B
    // total ws use: 88,670,208 B

    hipLaunchKernelGGL(prep_w1, dim3((N_ * KPAD_ + 255) / 256), dim3(256), 0, stream, W1, w1t);
    hipLaunchKernelGGL(prep_w2, dim3((N_ * N_) / 256), dim3(256), 0, stream, W2, w2t);
    hipLaunchKernelGGL(write_npatch, dim3(1), dim3(128), 0, stream, lengths,
                       out + (long)M_ * N_);
    hipLaunchKernelGGL(build_feat, dim3(M_), dim3(320), 0, stream, x, lengths, pos_table, feat);

    hipLaunchKernelGGL((gemm_bt<0>), dim3(M_ / 128, N_ / 128), dim3(256), 0, stream,
                       feat, w1t, b1, nullptr, h, nullptr, KPAD_);
    hipLaunchKernelGGL((gemm_bt<1>), dim3(M_ / 128, N_ / 128), dim3(256), 0, stream,
                       h, w2t, b2, lengths, nullptr, out, N_);
}